// Round 9
// baseline (70.397 us; speedup 1.0000x reference)
//
#include <hip/hip_runtime.h>
#include <math.h>

#define NROWS 512      // b*c = 8*64
#define NFEAT 4968     // 2*207*12
#define NVEC4 1242     // NFEAT/4 float4 per row
#define KSLICES 6
#define SLICE4 207     // float4 per K-slice (1242/6)
#define GSL 1242       // gmm elements per slice (NFEAT/4)
#define NGBLK (NROWS * 4)          // 2048 gmm blocks
#define WPB 20                     // flag words per gmm block: 5 iters * 4 waves
#define NWORDS (NGBLK * WPB)       // 40960
#define HALF_LOG2PI 0.91893853320467274178032973640562

// ---------------------------------------------------------------------------
// Phase 1: split-K row-tiled projection partials (f64).
// 8 rows/block: 64 rowtiles * 3 jgroups * 6 kslices = 1152 blocks.
// Per-(row,j,sl) summation order identical to r8 -> pp bit-identical.
// ---------------------------------------------------------------------------
__global__ __launch_bounds__(256) void proj_kernel(
    const float* __restrict__ x,
    const float* __restrict__ aw,
    const float* __restrict__ sw,
    const float* __restrict__ mw,
    double* __restrict__ pp)
{
    const int rt = blockIdx.x & 63;           // rowtile 0..63
    const int jg = (blockIdx.x >> 6) % 3;
    const int sl = blockIdx.x / 192;
    const int t = threadIdx.x;
    const int j = t >> 4;
    const int s16 = t & 15;
    const int row0 = rt * 8;

    const float* W = (jg == 0) ? aw : (jg == 1) ? sw : mw;
    const float4* wp = (const float4*)(W + (size_t)j * NFEAT) + sl * SLICE4;
    const float4* xp = (const float4*)(x + (size_t)row0 * NFEAT) + sl * SLICE4;

    double acc[8][2];
    #pragma unroll
    for (int r = 0; r < 8; ++r) { acc[r][0] = 0.0; acc[r][1] = 0.0; }

    for (int i = s16; i < SLICE4; i += 16) {
        float4 wv = wp[i];
        #pragma unroll
        for (int r = 0; r < 8; ++r) {
            float4 xv = xp[(size_t)r * NVEC4 + i];
            acc[r][0] = fma((double)xv.x, (double)wv.x, acc[r][0]);
            acc[r][0] = fma((double)xv.y, (double)wv.y, acc[r][0]);
            acc[r][1] = fma((double)xv.z, (double)wv.z, acc[r][1]);
            acc[r][1] = fma((double)xv.w, (double)wv.w, acc[r][1]);
        }
    }

    #pragma unroll
    for (int r = 0; r < 8; ++r) {
        double a = acc[r][0] + acc[r][1];
        #pragma unroll
        for (int off = 8; off; off >>= 1) a += __shfl_xor(a, off, 16);
        if (s16 == 0)
            pp[((size_t)(row0 + r) * 48 + jg * 16 + j) * KSLICES + sl] = a;
    }
}

// ---------------------------------------------------------------------------
// Phase 2: per-(row,k) parameter derivation (f64, bit-identical math).
// Emits f64 arrays (fixup/loss) + fp32 arrays (gmm hot path + epilogue).
// ---------------------------------------------------------------------------
__global__ __launch_bounds__(256) void params_kernel(
    const double* __restrict__ pp,
    const float* __restrict__ ab,
    const float* __restrict__ sb,
    const float* __restrict__ mb,
    double* __restrict__ mu, double* __restrict__ isg, double* __restrict__ cl,
    double* __restrict__ sig, double* __restrict__ ivp, double* __restrict__ lsg_o,
    float* __restrict__ muf, float* __restrict__ nhisg2f, float* __restrict__ clf,
    float* __restrict__ la, float* __restrict__ al,
    float* __restrict__ sigf, float* __restrict__ ivpf)
{
    const int g = blockIdx.x * 256 + threadIdx.x;   // 0..8191
    const int row = g >> 4, k = g & 15;
    const double* p = pp + ((size_t)row * 48 + k) * KSLICES;

    double pa = 0.0, ps = 0.0, pm = 0.0;
    #pragma unroll
    for (int s = 0; s < KSLICES; ++s) {
        pa += p[s];
        ps += p[16 * KSLICES + s];
        pm += p[32 * KSLICES + s];
    }
    pa += (double)ab[k]; ps += (double)sb[k]; pm += (double)mb[k];

    // softmax over 16 components (max-subtracted, like jax.nn.softmax)
    double m = pa;
    #pragma unroll
    for (int off = 8; off; off >>= 1) m = fmax(m, __shfl_xor(m, off, 16));
    double e = exp(pa - m);
    double ss = e;
    #pragma unroll
    for (int off = 8; off; off >>= 1) ss += __shfl_xor(ss, off, 16);
    double alpha = e / ss;
    double lav = log(alpha);

    double sg  = exp(ps);
    double lsg = log(sg);

    double isgv = 1.0 / sg;
    double clv  = lav - lsg - HALF_LOG2PI;   // lp = cl - 0.5*z^2
    double ivpv = 1.0 / (sg + 1e-5);

    mu[g]  = pm;
    isg[g] = isgv;
    cl[g]  = clv;
    sig[g] = sg;
    ivp[g] = ivpv;
    lsg_o[g] = lsg;
    muf[g]     = (float)pm;
    nhisg2f[g] = (float)(-0.5 * isgv * isgv);
    clf[g]     = (float)clv;
    la[g]   = (float)lav;
    al[g]   = (float)alpha;
    sigf[g] = (float)sg;
    ivpf[g] = (float)ivpv;
}

// ---------------------------------------------------------------------------
// Phase 3: GMM pass, pure fp32 (hot loop identical to r8; fp32 epilogue).
// No atomics: near-ties recorded via per-wave ballot bitmap.
// ---------------------------------------------------------------------------
__global__ __launch_bounds__(256, 2) void gmm_kernel(
    const float* __restrict__ x,
    const float* __restrict__ muf, const float* __restrict__ nhisg2f,
    const float* __restrict__ clf, const float* __restrict__ laf,
    const float* __restrict__ sigf, const float* __restrict__ ivpf,
    float* __restrict__ out,
    double* __restrict__ shp, double* __restrict__ sh2p,
    float* __restrict__ S2p, float* __restrict__ FIp,
    unsigned long long* __restrict__ flagwords)
{
    const int row = blockIdx.x >> 2;
    const int sl  = blockIdx.x & 3;
    const int tid = threadIdx.x;
    const int g0  = row * 16;

    __shared__ float sig_s[16], ivp_s[16];
    __shared__ double redd[4][2];
    __shared__ float  redf[4][2];

    if (tid < 16) {
        sig_s[tid] = sigf[g0 + tid];
        ivp_s[tid] = ivpf[g0 + tid];
    }
    __syncthreads();

    float mu_r[16], ns_r[16], cl_r[16], la_r[16];
    #pragma unroll
    for (int k = 0; k < 16; ++k) {
        mu_r[k] = muf[g0 + k];
        ns_r[k] = nhisg2f[g0 + k];
        cl_r[k] = clf[g0 + k];
        la_r[k] = laf[g0 + k];
    }
    // Pin params in VGPRs (prevents per-iteration rematerializing loads).
    #pragma unroll
    for (int k = 0; k < 16; ++k) {
        asm volatile("" : "+v"(mu_r[k]), "+v"(ns_r[k]),
                          "+v"(cl_r[k]), "+v"(la_r[k]));
    }

    double sh = 0.0, sh2 = 0.0;
    float S2 = 0.f, FI = 0.f;

    const int base = sl * GSL;
    const float* xr = x + (size_t)row * NFEAT + base;
    float* outr = out + (size_t)row * NFEAT + base;
    const int wave = tid >> 6;
    unsigned long long* fw = flagwords + (size_t)blockIdx.x * WPB;

    for (int it = 0, n = tid; n < GSL; ++it, n += 256) {
        float h = xr[n];
        float max1 = -3.4e38f, max2 = -3.4e38f;
        int lab = 0;
        float sumexp = 0.f, s1 = 0.f;
        #pragma unroll
        for (int k = 0; k < 16; ++k) {
            float d  = h - mu_r[k];
            float lp = fmaf(d * d, ns_r[k], cl_r[k]);
            max2 = fmaxf(fminf(lp, max1), max2);   // 2nd max (branchless)
            lab  = (lp > max1) ? k : lab;
            max1 = fmaxf(lp, max1);
            float e = __expf(lp);
            sumexp += e;
            s1 = fmaf(e, lp - la_r[k], s1);
        }
        S2 += __logf(sumexp);        // log-sum-exp WITHOUT max-sub (matches ref)
        FI += __fdividef(s1, sumexp);
        sh += (double)h;
        sh2 = fma((double)h, (double)h, sh2);

        outr[n] = (h - sig_s[lab]) * ivp_s[lab];   // fp32 epilogue

        // near-tie bitmap: one plain store per wave per iter, no atomics
        unsigned long long mask = __ballot(max1 - max2 < 1e-3f);
        if ((tid & 63) == 0) fw[it * 4 + wave] = mask;
    }

    // --- block-reduce {sh, sh2 (f64), S2, FI (f32)} ---
    #pragma unroll
    for (int off = 32; off; off >>= 1) {
        sh  += __shfl_xor(sh,  off, 64);
        sh2 += __shfl_xor(sh2, off, 64);
        S2  += __shfl_xor(S2,  off, 64);
        FI  += __shfl_xor(FI,  off, 64);
    }
    const int lane = tid & 63;
    if (lane == 0) {
        redd[wave][0] = sh;  redd[wave][1] = sh2;
        redf[wave][0] = S2;  redf[wave][1] = FI;
    }
    __syncthreads();
    if (tid == 0) {
        shp[blockIdx.x]  = redd[0][0] + redd[1][0] + redd[2][0] + redd[3][0];
        sh2p[blockIdx.x] = redd[0][1] + redd[1][1] + redd[2][1] + redd[3][1];
        S2p[blockIdx.x]  = redf[0][0] + redf[1][0] + redf[2][0] + redf[3][0];
        FIp[blockIdx.x]  = redf[0][1] + redf[1][1] + redf[2][1] + redf[3][1];
    }
}

// ---------------------------------------------------------------------------
// Phase 4: fixup (parallel bitmap scan, exact f64, bit-identical formula)
// + loss reduce (done by block 0 after its fixup share).
// ---------------------------------------------------------------------------
__global__ __launch_bounds__(256) void tail_kernel(
    const float* __restrict__ x,
    const double* __restrict__ mu, const double* __restrict__ isg,
    const double* __restrict__ cl,
    const double* __restrict__ sig, const double* __restrict__ ivp,
    const double* __restrict__ lsg, const float* __restrict__ al,
    const unsigned long long* __restrict__ flagwords,
    const double* __restrict__ shp, const double* __restrict__ sh2p,
    const float* __restrict__ S2p, const float* __restrict__ FIp,
    float* __restrict__ out, float* __restrict__ loss_out)
{
    const int tid = threadIdx.x;

    // ---- fixup scan (all 128 blocks) ----
    for (int w = blockIdx.x * 256 + tid; w < NWORDS; w += 128 * 256) {
        unsigned long long bits = flagwords[w];
        if (!bits) continue;
        const int blk  = w / WPB;
        const int r20  = w - blk * WPB;
        const int it   = r20 >> 2;
        const int wv   = r20 & 3;
        const int row  = blk >> 2;
        const int sl   = blk & 3;
        const int g0   = row * 16;
        const int nbase = it * 256 + wv * 64;
        while (bits) {
            int b = __builtin_ctzll(bits);
            bits &= bits - 1;
            int n = nbase + b;
            if (n >= GSL) continue;
            size_t eid = (size_t)row * NFEAT + sl * GSL + n;
            double hd = (double)x[eid];
            double maxlp = -1.0e300;
            int lab = 0;
            #pragma unroll
            for (int k = 0; k < 16; ++k) {
                double zd  = (hd - mu[g0 + k]) * isg[g0 + k];
                double lpd = fma(zd * zd, -0.5, cl[g0 + k]);
                if (lpd > maxlp) { maxlp = lpd; lab = k; }
            }
            out[eid] = (float)((hd - sig[g0 + lab]) * ivp[g0 + lab]);
        }
    }

    // ---- loss reduce (block 0 only) ----
    if (blockIdx.x == 0) {
        const double Nd = (double)NFEAT;
        double kl_acc = 0.0;
        for (int g = tid; g < 8192; g += 256) {
            int row = g >> 4;
            int b = row * 4;
            double sh  = shp[b + 0] + shp[b + 1] + shp[b + 2] + shp[b + 3];
            double sh2 = sh2p[b + 0] + sh2p[b + 1] + sh2p[b + 2] + sh2p[b + 3];
            float  s2f = S2p[b + 0] + S2p[b + 1] + S2p[b + 2] + S2p[b + 3];
            double m  = mu[g];
            double iv = isg[g];
            double ns = -0.5 * iv * iv;
            double S1 = Nd * (-lsg[g] - HALF_LOG2PI)
                      + ns * (sh2 - 2.0 * m * sh + Nd * m * m);
            kl_acc += (double)al[g] * ((double)s2f - S1) / Nd;
        }
        float fi_acc = 0.f;
        for (int i = tid; i < 2048; i += 256) fi_acc += FIp[i];

        #pragma unroll
        for (int off = 32; off; off >>= 1) {
            kl_acc += __shfl_xor(kl_acc, off, 64);
            fi_acc += __shfl_xor(fi_acc, off, 64);
        }
        __shared__ double ra[4];
        __shared__ float  rb[4];
        const int wv = tid >> 6, lane = tid & 63;
        if (lane == 0) { ra[wv] = kl_acc; rb[wv] = fi_acc; }
        __syncthreads();
        if (tid == 0) {
            double ka = ra[0] + ra[1] + ra[2] + ra[3];
            float  kb = rb[0] + rb[1] + rb[2] + rb[3];
            // kl mean over (b,c,K)=8192 ; first_item mean over 40697856
            loss_out[0] = (float)(ka / 8192.0 - (double)kb / 40697856.0);
        }
    }
}

extern "C" void kernel_launch(void* const* d_in, const int* in_sizes, int n_in,
                              void* d_out, int out_size, void* d_ws, size_t ws_size,
                              hipStream_t stream) {
    const float* x  = (const float*)d_in[0];
    const float* aw = (const float*)d_in[1];
    const float* ab = (const float*)d_in[2];
    const float* sw = (const float*)d_in[3];
    const float* sb = (const float*)d_in[4];
    const float* mw = (const float*)d_in[5];
    const float* mb = (const float*)d_in[6];
    float* out = (float*)d_out;

    double* pp   = (double*)d_ws;                       // 512*48*6 f64
    double* mu   = pp + (size_t)NROWS * 48 * KSLICES;
    double* isg  = mu + 8192;
    double* cl   = isg + 8192;
    double* sig  = cl + 8192;
    double* ivp  = sig + 8192;
    double* lsg  = ivp + 8192;
    double* shp  = lsg + 8192;              // 2048 f64
    double* sh2p = shp + NGBLK;             // 2048 f64
    unsigned long long* flagwords = (unsigned long long*)(sh2p + NGBLK); // 40960
    float* muf     = (float*)(flagwords + NWORDS);
    float* nhisg2f = muf + 8192;
    float* clf     = nhisg2f + 8192;
    float* la      = clf + 8192;
    float* al      = la + 8192;
    float* sigf    = al + 8192;
    float* ivpf    = sigf + 8192;
    float* S2p     = ivpf + 8192;           // 2048
    float* FIp     = S2p + NGBLK;           // 2048

    proj_kernel<<<64 * 3 * KSLICES, 256, 0, stream>>>(x, aw, sw, mw, pp);
    params_kernel<<<32, 256, 0, stream>>>(pp, ab, sb, mb,
                                          mu, isg, cl, sig, ivp, lsg,
                                          muf, nhisg2f, clf, la, al, sigf, ivpf);
    gmm_kernel<<<NGBLK, 256, 0, stream>>>(x, muf, nhisg2f, clf, la, sigf, ivpf,
                                          out, shp, sh2p, S2p, FIp, flagwords);
    tail_kernel<<<128, 256, 0, stream>>>(x, mu, isg, cl, sig, ivp, lsg, al,
                                         flagwords, shp, sh2p, S2p, FIp,
                                         out, out + (size_t)NROWS * NFEAT);
}